// Round 1
// baseline (1214.763 us; speedup 1.0000x reference)
//
#include <hip/hip_runtime.h>

// SigLipAttention: B=32 S=576 H=12 D=64 E=768
// out  = fp32 [B,S,E]            @ d_out
// attn = fp32 [B,H,S,S] softmax  @ d_out + 14155776
//
// Pipeline:
//  cvt_split  : X, q_w, k_w -> bf16 hi/lo ; v_w, o_w -> bf16 hi
//  gemm128    : q = X@q_w^T+b (split, out hi/lo), k likewise, v (plain, bf16)
//  attn_softmax: scores (split MFMA) -> softmax fp32 -> attn (d_out)
//  pv         : out_pre = attn@v (plain bf16)
//  gemm128    : out = out_pre@o_w^T + o_b (fp32 -> d_out)

#define B_ 32
#define S_ 576
#define H_ 12
#define D_ 64
#define E_ 768
#define M_ (B_ * S_)          // 18432

typedef __attribute__((ext_vector_type(8))) short bf16x8;
typedef __attribute__((ext_vector_type(4))) float f32x4;
typedef __attribute__((ext_vector_type(4))) unsigned short u16x4;
typedef __attribute__((ext_vector_type(8))) unsigned short u16x8;

#define MFMA16(a, b, c) __builtin_amdgcn_mfma_f32_16x16x32_bf16(a, b, c, 0, 0, 0)

__device__ __forceinline__ unsigned short f2bf(float x) {
  union { float f; unsigned u; } v; v.f = x;
  unsigned r = v.u + 0x7fffu + ((v.u >> 16) & 1u);   // RNE
  return (unsigned short)(r >> 16);
}
__device__ __forceinline__ float bf2f(unsigned short h) {
  union { unsigned u; float f; } v; v.u = ((unsigned)h) << 16; return v.f;
}

// ---------------- fp32 -> bf16 hi (+ optional lo) ----------------
__global__ __launch_bounds__(256) void cvt_split(const float* __restrict__ in,
                                                 unsigned short* __restrict__ hi,
                                                 unsigned short* __restrict__ lo,
                                                 int n4) {
  int i = blockIdx.x * 256 + threadIdx.x;
  if (i >= n4) return;
  float4 x = ((const float4*)in)[i];
  u16x4 h;
  h[0] = f2bf(x.x); h[1] = f2bf(x.y); h[2] = f2bf(x.z); h[3] = f2bf(x.w);
  ((u16x4*)hi)[i] = h;
  if (lo) {
    u16x4 l;
    l[0] = f2bf(x.x - bf2f(h[0])); l[1] = f2bf(x.y - bf2f(h[1]));
    l[2] = f2bf(x.z - bf2f(h[2])); l[3] = f2bf(x.w - bf2f(h[3]));
    ((u16x4*)lo)[i] = l;
  }
}

// ---------------- NT GEMM: C[m,n] = sum_k A[m,k]*B[n,k] + bias[n] ----------------
// A,B given as bf16 hi (and lo when SPLIT). 128x128 tile, BK=32, 256 threads.
// OUT_MODE: 0 = fp32 C0 ; 1 = bf16 C0 ; 2 = bf16 split C0(hi)/C1(lo)
template <bool SPLIT, int OUT_MODE>
__global__ __launch_bounds__(256)
void gemm128(const unsigned short* __restrict__ Ahg, const unsigned short* __restrict__ Alg,
             const unsigned short* __restrict__ Bhg, const unsigned short* __restrict__ Blg,
             const float* __restrict__ bias, void* __restrict__ C0, void* __restrict__ C1,
             int Kd, int lda, int ldb, int ldc) {
  constexpr int BM = 128, BN = 128, BK = 32, LSTR = BK + 8;  // +8 halves pad
  __shared__ __attribute__((aligned(16))) unsigned short Ah[BM * LSTR];
  __shared__ __attribute__((aligned(16))) unsigned short Bh[BN * LSTR];
  __shared__ __attribute__((aligned(16))) unsigned short Al[SPLIT ? BM * LSTR : 8];
  __shared__ __attribute__((aligned(16))) unsigned short Bl[SPLIT ? BN * LSTR : 8];

  const int tid = threadIdx.x, lane = tid & 63, wv = tid >> 6;
  const int wm = (wv & 1) * 64, wn = (wv >> 1) * 64;
  const long m0 = (long)blockIdx.y * BM, n0 = (long)blockIdx.x * BN;
  const int fr = lane & 15, g8 = (lane >> 4) * 8;

  f32x4 acc[4][4] = {};

  for (int kt = 0; kt < Kd; kt += BK) {
    __syncthreads();
    for (int i = tid; i < BM * BK / 8; i += 256) {  // 512 chunks of 8 halves
      int row = i >> 2, c8 = (i & 3) * 8;
      *(u16x8*)&Ah[row * LSTR + c8] = *(const u16x8*)(Ahg + (m0 + row) * lda + kt + c8);
      *(u16x8*)&Bh[row * LSTR + c8] = *(const u16x8*)(Bhg + (n0 + row) * ldb + kt + c8);
      if (SPLIT) {
        *(u16x8*)&Al[row * LSTR + c8] = *(const u16x8*)(Alg + (m0 + row) * lda + kt + c8);
        *(u16x8*)&Bl[row * LSTR + c8] = *(const u16x8*)(Blg + (n0 + row) * ldb + kt + c8);
      }
    }
    __syncthreads();
    bf16x8 ah[4], bh[4], al[4], bl[4];
#pragma unroll
    for (int mi = 0; mi < 4; ++mi) {
      ah[mi] = *(const bf16x8*)&Ah[(wm + mi * 16 + fr) * LSTR + g8];
      if (SPLIT) al[mi] = *(const bf16x8*)&Al[(wm + mi * 16 + fr) * LSTR + g8];
    }
#pragma unroll
    for (int ni = 0; ni < 4; ++ni) {
      bh[ni] = *(const bf16x8*)&Bh[(wn + ni * 16 + fr) * LSTR + g8];
      if (SPLIT) bl[ni] = *(const bf16x8*)&Bl[(wn + ni * 16 + fr) * LSTR + g8];
    }
#pragma unroll
    for (int mi = 0; mi < 4; ++mi)
#pragma unroll
      for (int ni = 0; ni < 4; ++ni) {
        acc[mi][ni] = MFMA16(ah[mi], bh[ni], acc[mi][ni]);
        if (SPLIT) {
          acc[mi][ni] = MFMA16(ah[mi], bl[ni], acc[mi][ni]);
          acc[mi][ni] = MFMA16(al[mi], bh[ni], acc[mi][ni]);
        }
      }
  }

#pragma unroll
  for (int mi = 0; mi < 4; ++mi)
#pragma unroll
    for (int ni = 0; ni < 4; ++ni) {
      long col = n0 + wn + ni * 16 + fr;
      long rb = m0 + wm + mi * 16 + (lane >> 4) * 4;
      float bv = bias ? bias[col] : 0.f;
#pragma unroll
      for (int r = 0; r < 4; ++r) {
        float v = acc[mi][ni][r] + bv;
        long idx = (rb + r) * ldc + col;
        if (OUT_MODE == 0) {
          ((float*)C0)[idx] = v;
        } else if (OUT_MODE == 1) {
          ((unsigned short*)C0)[idx] = f2bf(v);
        } else {
          unsigned short hh = f2bf(v);
          ((unsigned short*)C0)[idx] = hh;
          ((unsigned short*)C1)[idx] = f2bf(v - bf2f(hh));
        }
      }
    }
}

// ---------------- scores + softmax -> attn (fp32) ----------------
// grid (18, 12, 32) = (qtile, h, b). 32 q-rows per block, scores in registers.
// Wave wv: rows (wv&1)*16..+16 ; cols (per 64-col k-tile) (wv>>1)*32..+32.
__global__ __launch_bounds__(256)
void attn_softmax(const unsigned short* __restrict__ qh, const unsigned short* __restrict__ ql,
                  const unsigned short* __restrict__ kh, const unsigned short* __restrict__ kl,
                  float* __restrict__ attn) {
  constexpr int LQ = 72;  // 64 + 8 pad (halves)
  __shared__ __attribute__((aligned(16))) unsigned short qhl[32 * LQ], qll[32 * LQ];
  __shared__ __attribute__((aligned(16))) unsigned short khl[64 * LQ], kll[64 * LQ];
  __shared__ float redm[2][32], reds[2][32];

  const int tid = threadIdx.x, lane = tid & 63, wv = tid >> 6;
  const int qt = blockIdx.x, h = blockIdx.y, b = blockIdx.z;
  const int fr = lane & 15, gq = lane >> 4;
  const int mg = (wv & 1), ch = (wv >> 1);

  // stage q tile: 32 rows x 64 halves (hi+lo), one u16x8 per thread per array
  {
    int row = tid >> 3, c8 = (tid & 7) * 8;
    long qb = ((long)(b * S_ + qt * 32 + row)) * E_ + h * 64 + c8;
    *(u16x8*)&qhl[row * LQ + c8] = *(const u16x8*)(qh + qb);
    *(u16x8*)&qll[row * LQ + c8] = *(const u16x8*)(ql + qb);
  }
  __syncthreads();
  bf16x8 qa_h[2], qa_l[2];
#pragma unroll
  for (int kc = 0; kc < 2; ++kc) {
    qa_h[kc] = *(const bf16x8*)&qhl[(mg * 16 + fr) * LQ + kc * 32 + gq * 8];
    qa_l[kc] = *(const bf16x8*)&qll[(mg * 16 + fr) * LQ + kc * 32 + gq * 8];
  }

  f32x4 acc[9][2] = {};
  for (int kt = 0; kt < 9; ++kt) {
    __syncthreads();
    for (int i = tid; i < 512; i += 256) {
      int row = i >> 3, c8 = (i & 7) * 8;
      long kb = ((long)(b * S_ + kt * 64 + row)) * E_ + h * 64 + c8;
      *(u16x8*)&khl[row * LQ + c8] = *(const u16x8*)(kh + kb);
      *(u16x8*)&kll[row * LQ + c8] = *(const u16x8*)(kl + kb);
    }
    __syncthreads();
#pragma unroll
    for (int kc = 0; kc < 2; ++kc) {
#pragma unroll
      for (int nf = 0; nf < 2; ++nf) {
        bf16x8 b_h = *(const bf16x8*)&khl[(ch * 32 + nf * 16 + fr) * LQ + kc * 32 + gq * 8];
        bf16x8 b_l = *(const bf16x8*)&kll[(ch * 32 + nf * 16 + fr) * LQ + kc * 32 + gq * 8];
        acc[kt][nf] = MFMA16(qa_h[kc], b_h, acc[kt][nf]);
        acc[kt][nf] = MFMA16(qa_h[kc], b_l, acc[kt][nf]);
        acc[kt][nf] = MFMA16(qa_l[kc], b_h, acc[kt][nf]);
      }
    }
  }

  // ---- softmax over 576 cols, rows distributed: lane holds rows mg*16+gq*4+r,
  // cols kt*64 + ch*32 + nf*16 + fr  (x0.125 scale applied here)
  const float SC = 0.125f;
  float M[4], Sv[4];
#pragma unroll
  for (int r = 0; r < 4; ++r) {
    float pm = -1e30f;
#pragma unroll
    for (int kt = 0; kt < 9; ++kt)
#pragma unroll
      for (int nf = 0; nf < 2; ++nf) pm = fmaxf(pm, acc[kt][nf][r] * SC);
    for (int off = 1; off < 16; off <<= 1) pm = fmaxf(pm, __shfl_xor(pm, off));
    M[r] = pm;
  }
  if (fr == 0) {
#pragma unroll
    for (int r = 0; r < 4; ++r) redm[ch][mg * 16 + gq * 4 + r] = M[r];
  }
  __syncthreads();
#pragma unroll
  for (int r = 0; r < 4; ++r)
    M[r] = fmaxf(redm[0][mg * 16 + gq * 4 + r], redm[1][mg * 16 + gq * 4 + r]);

#pragma unroll
  for (int r = 0; r < 4; ++r) {
    float ps = 0.f;
#pragma unroll
    for (int kt = 0; kt < 9; ++kt)
#pragma unroll
      for (int nf = 0; nf < 2; ++nf) {
        float e = __expf(acc[kt][nf][r] * SC - M[r]);
        acc[kt][nf][r] = e;
        ps += e;
      }
    for (int off = 1; off < 16; off <<= 1) ps += __shfl_xor(ps, off);
    Sv[r] = ps;
  }
  if (fr == 0) {
#pragma unroll
    for (int r = 0; r < 4; ++r) reds[ch][mg * 16 + gq * 4 + r] = Sv[r];
  }
  __syncthreads();
#pragma unroll
  for (int r = 0; r < 4; ++r)
    Sv[r] = 1.f / (reds[0][mg * 16 + gq * 4 + r] + reds[1][mg * 16 + gq * 4 + r]);

  float* out = attn + ((long)((b * H_ + h) * S_) + qt * 32) * S_;
#pragma unroll
  for (int kt = 0; kt < 9; ++kt)
#pragma unroll
    for (int nf = 0; nf < 2; ++nf)
#pragma unroll
      for (int r = 0; r < 4; ++r) {
        long row = mg * 16 + gq * 4 + r;
        long col = kt * 64 + ch * 32 + nf * 16 + fr;
        out[row * S_ + col] = acc[kt][nf][r] * Sv[r];
      }
}

// ---------------- PV: out_pre[b,s,h*64+d] = sum_k attn[b,h,s,k] * v[b,k,h*64+d] ----------------
// grid (9, 384) = (mtile of 64 rows, b*12+h). Plain bf16.
__global__ __launch_bounds__(256)
void pv_kernel(const float* __restrict__ attn, const unsigned short* __restrict__ v,
               unsigned short* __restrict__ out_pre) {
  constexpr int LSTR = 40;
  __shared__ __attribute__((aligned(16))) unsigned short A_lds[64 * LSTR];  // attn tile [row][k]
  __shared__ __attribute__((aligned(16))) unsigned short B_lds[64 * LSTR];  // v^T tile [d][k]

  const int tid = threadIdx.x, lane = tid & 63, wv = tid >> 6;
  const int mt = blockIdx.x, z = blockIdx.y;
  const int b = z / 12, h = z % 12;
  const int wm = (wv & 1) * 32, wn = (wv >> 1) * 32;
  const int fr = lane & 15, g8 = (lane >> 4) * 8;

  const float* Ab = attn + (long)z * S_ * S_ + (long)mt * 64 * S_;
  const unsigned short* Vb = v + (long)b * S_ * E_ + h * 64;

  f32x4 acc[2][2] = {};
  for (int kt = 0; kt < S_; kt += 32) {
    __syncthreads();
    for (int i = tid; i < 512; i += 256) {  // attn 64x32 fp32 -> bf16
      int row = i >> 3, c4 = (i & 7) * 4;
      float4 x = *(const float4*)(Ab + (long)row * S_ + kt + c4);
      u16x4 hh;
      hh[0] = f2bf(x.x); hh[1] = f2bf(x.y); hh[2] = f2bf(x.z); hh[3] = f2bf(x.w);
      *(u16x4*)&A_lds[row * LSTR + c4] = hh;
    }
    for (int i = tid; i < 512; i += 256) {  // v 32x64 -> transposed [d][k]
      int kk = i >> 4, d4 = (i & 15) * 4;
      u16x4 x = *(const u16x4*)(Vb + (long)(kt + kk) * E_ + d4);
#pragma unroll
      for (int j = 0; j < 4; ++j) B_lds[(d4 + j) * LSTR + kk] = x[j];
    }
    __syncthreads();
    bf16x8 af[2], bfv[2];
#pragma unroll
    for (int mi = 0; mi < 2; ++mi) af[mi] = *(const bf16x8*)&A_lds[(wm + mi * 16 + fr) * LSTR + g8];
#pragma unroll
    for (int ni = 0; ni < 2; ++ni) bfv[ni] = *(const bf16x8*)&B_lds[(wn + ni * 16 + fr) * LSTR + g8];
#pragma unroll
    for (int mi = 0; mi < 2; ++mi)
#pragma unroll
      for (int ni = 0; ni < 2; ++ni) acc[mi][ni] = MFMA16(af[mi], bfv[ni], acc[mi][ni]);
  }

#pragma unroll
  for (int mi = 0; mi < 2; ++mi)
#pragma unroll
    for (int ni = 0; ni < 2; ++ni)
#pragma unroll
      for (int r = 0; r < 4; ++r) {
        long row = (long)mt * 64 + wm + mi * 16 + (lane >> 4) * 4 + r;
        long col = wn + ni * 16 + fr;
        out_pre[((long)b * S_ + row) * E_ + h * 64 + col] = f2bf(acc[mi][ni][r]);
      }
}

// ---------------- host ----------------
extern "C" void kernel_launch(void* const* d_in, const int* in_sizes, int n_in,
                              void* d_out, int out_size, void* d_ws, size_t ws_size,
                              hipStream_t stream) {
  const float* X = (const float*)d_in[0];
  const float* q_w = (const float*)d_in[1];
  const float* q_b = (const float*)d_in[2];
  const float* k_w = (const float*)d_in[3];
  const float* k_b = (const float*)d_in[4];
  const float* v_w = (const float*)d_in[5];
  const float* v_b = (const float*)d_in[6];
  const float* o_w = (const float*)d_in[7];
  const float* o_b = (const float*)d_in[8];

  const long NX = (long)M_ * E_;       // 14155776
  const long NW = (long)E_ * E_;       // 589824

  unsigned short* w = (unsigned short*)d_ws;
  unsigned short* Xhi = w;
  unsigned short* Xlo = Xhi + NX;
  unsigned short* qwh = Xlo + NX;
  unsigned short* qwl = qwh + NW;
  unsigned short* kwh = qwl + NW;
  unsigned short* kwl = kwh + NW;
  unsigned short* vwh = kwl + NW;
  unsigned short* owh = vwh + NW;
  unsigned short* Qhi = owh + NW;
  unsigned short* Qlo = Qhi + NX;
  unsigned short* Khi = Qlo + NX;
  unsigned short* Klo = Khi + NX;
  unsigned short* Vw  = Klo + NX;
  unsigned short* Opre = Vw + NX;
  // total: 8*NX + 6*NW halves = 233,570,304 bytes of d_ws

  float* out_f = (float*)d_out;
  float* attn_f = (float*)d_out + NX;

  // 1) pre-split conversions
  cvt_split<<<dim3((NX / 4 + 255) / 256), dim3(256), 0, stream>>>(X, Xhi, Xlo, NX / 4);
  cvt_split<<<dim3((NW / 4 + 255) / 256), dim3(256), 0, stream>>>(q_w, qwh, qwl, NW / 4);
  cvt_split<<<dim3((NW / 4 + 255) / 256), dim3(256), 0, stream>>>(k_w, kwh, kwl, NW / 4);
  cvt_split<<<dim3((NW / 4 + 255) / 256), dim3(256), 0, stream>>>(v_w, vwh, nullptr, NW / 4);
  cvt_split<<<dim3((NW / 4 + 255) / 256), dim3(256), 0, stream>>>(o_w, owh, nullptr, NW / 4);

  dim3 gproj(E_ / 128, M_ / 128);  // (6, 144)
  // 2) projections
  gemm128<true, 2><<<gproj, dim3(256), 0, stream>>>(Xhi, Xlo, qwh, qwl, q_b, Qhi, Qlo, E_, E_, E_, E_);
  gemm128<true, 2><<<gproj, dim3(256), 0, stream>>>(Xhi, Xlo, kwh, kwl, k_b, Khi, Klo, E_, E_, E_, E_);
  gemm128<false, 1><<<gproj, dim3(256), 0, stream>>>(Xhi, nullptr, vwh, nullptr, v_b, Vw, nullptr, E_, E_, E_, E_);

  // 3) scores + softmax -> attn
  attn_softmax<<<dim3(S_ / 32, H_, B_), dim3(256), 0, stream>>>(Qhi, Qlo, Khi, Klo, attn_f);

  // 4) attn @ V -> out_pre (bf16)
  pv_kernel<<<dim3(S_ / 64, B_ * H_), dim3(256), 0, stream>>>(attn_f, Vw, Opre);

  // 5) O projection -> out (fp32)
  gemm128<false, 0><<<gproj, dim3(256), 0, stream>>>(Opre, nullptr, owh, nullptr, o_b, out_f, nullptr, E_, E_, E_, E_);
}